// Round 3
// baseline (664.048 us; speedup 1.0000x reference)
//
#include <hip/hip_runtime.h>

#define B_DIM 1024
#define NT 128
#define NY 128
#define C_DIM 512
#define EOS 1
#define TT 32     // t-tile size (4 tiles cover NT)
#define XP 130    // LDS row stride in floats: 130%32=2 -> 2-way bank aliasing (free)

// ---------------- DPP helpers (gfx9 lineage: row_shr / row_bcast / wave_shr) --------
template <int CTRL, int RM>
__device__ __forceinline__ float dpp_mov_f(float src, float oldv) {
    return __int_as_float(__builtin_amdgcn_update_dpp(
        __float_as_int(oldv), __float_as_int(src), CTRL, RM, 0xf, false));
}

__device__ __forceinline__ float wave_shr1_f(float src, float oldv) {
    return dpp_mov_f<0x138, 0xf>(src, oldv);   // wave_shr:1, lane 0 gets oldv
}

template <int CTRL, int RM>
__device__ __forceinline__ void scan_stage(float& A, float& D) {
    const float Ap = dpp_mov_f<CTRL, RM>(A, 0.0f);
    const float Dp = dpp_mov_f<CTRL, RM>(D, 1.0f);
    A = fmaf(Ap, D, A);
    D = D * Dp;
}

__device__ __forceinline__ void affine_scan64(float& A, float& D) {
    scan_stage<0x111, 0xf>(A, D);   // row_shr:1
    scan_stage<0x112, 0xf>(A, D);   // row_shr:2
    scan_stage<0x114, 0xf>(A, D);   // row_shr:4
    scan_stage<0x118, 0xf>(A, D);   // row_shr:8
    scan_stage<0x142, 0xa>(A, D);   // row_bcast:15 -> rows 1,3
    scan_stage<0x143, 0xc>(A, D);   // row_bcast:31 -> rows 2,3
}

__device__ __forceinline__ float mul_scan64(float P) {
    P *= dpp_mov_f<0x111, 0xf>(P, 1.0f);
    P *= dpp_mov_f<0x112, 0xf>(P, 1.0f);
    P *= dpp_mov_f<0x114, 0xf>(P, 1.0f);
    P *= dpp_mov_f<0x118, 0xf>(P, 1.0f);
    P *= dpp_mov_f<0x142, 0xa>(P, 1.0f);
    P *= dpp_mov_f<0x143, 0xc>(P, 1.0f);
    return P;
}

// ---------------- Fused kernel: pipelined t-tiled gather + scan ----------------
// One block per b, 8 waves, static LDS only (no runtime attribute calls).
// Double-buffered [TT][j] tiles: waves 1-7 gather tile k+1 (transposing into
// [t][j] layout) while wave 0 runs 32 scan steps on tile k. No global G arrays,
// no workspace, writes = 4 KB total.
__global__ __launch_bounds__(512) void eploss_fused(
    const float* __restrict__ pred,
    const float* __restrict__ R,
    const float* __restrict__ I,
    const int*   __restrict__ target,
    float*       __restrict__ out)
{
    __shared__ float Xb[2][TT][XP];   // pred gather, [buf][t-within-tile][j]
    __shared__ float Yb[2][TT][XP];   // I    gather
    __shared__ int   tg[NT];

    const int b    = blockIdx.x;
    const int tid  = threadIdx.x;
    const int wave = tid >> 6;
    const int lane = tid & 63;

    if (tid < NT) tg[tid] = target[(size_t)b * NT + tid];
    __syncthreads();

    const float* __restrict__ predB = pred + (size_t)b * NY * C_DIM;
    const float* __restrict__ IB    = I    + (size_t)b * NY * C_DIM;

    // ---- prologue: all 512 threads gather tile 0 into buffer 0 ----
    {
        const int tt  = tid & 31;       // 512 % 32 == 0 -> tt fixed per thread
        const int tgt = tg[tt];         // tile 0 -> global t = tt
        #pragma unroll 8
        for (int row = tid >> 5; row < 2 * NY; row += 512 / 32) {
            const int j = row & (NY - 1);
            const float v = (row < NY ? predB : IB)[(size_t)j * C_DIM + tgt];
            (row < NY ? Xb : Yb)[0][tt][j] = v;
        }
    }

    // ---- wave 0: scan-state init (register-resident across tiles) ----
    const int j0 = 2 * lane;
    const int j1 = 2 * lane + 1;
    float R0j0, R1j0, R2j0, R0j1, R1j1, R2j1, R2m1, row0v, row1v;
    if (wave == 0) {
        const float* Rb = R + (size_t)b * NY * 3;
        R0j0 = Rb[j0 * 3 + 0];
        R1j0 = Rb[j0 * 3 + 1];
        R2j0 = Rb[j0 * 3 + 2];
        R0j1 = Rb[j1 * 3 + 0];
        R1j1 = Rb[j1 * 3 + 1];
        R2j1 = Rb[j1 * 3 + 2];
        R2m1 = wave_shr1_f(R2j1, 1.0f);   // R2[j0-1] (lane 0 value unused)

        // row0 = cumprod([1, pD0[1..127]])
        const int tgt0 = tg[0];
        const float e0 = (lane == 0) ? 1.0f : ((tgt0 == EOS) ? 1.0f : R2j0);
        const float e1 = (tgt0 == EOS) ? 1.0f : R2j1;
        float P = mul_scan64(e0 * e1);
        const float Pm1 = wave_shr1_f(P, 1.0f);   // lane 0 -> 1.0
        row0v = Pm1 * e0;
        row1v = P;
    }
    __syncthreads();   // tile 0 ready

    auto step = [&](float p0, float p1, float q0, float q1, int tgt_next) {
        const float pC0 = R0j0 * p0;
        const float pC1 = R0j1 * p1;
        const float pI0 = R1j0 * q0;
        const float pI1 = (lane == 63) ? q1 : R1j1 * q1;   // p_I[...,127] = I_T
        const float m1    = row1v * pC1;
        const float mprev = wave_shr1_f(m1, 0.0f);          // lane 0 -> 0
        const float a0 = fmaf(row0v, pI0, mprev);
        const float a1 = row0v * pC0 + row1v * pI1;
        const bool  eosn = (tgt_next == EOS);
        const float d0 = (lane == 0 || eosn) ? 1.0f : R2m1;
        const float d1 = eosn ? 1.0f : R2j0;
        float A = fmaf(d1, a0, a1);
        float D = d1 * d0;
        affine_scan64(A, D);
        const float Xm1 = wave_shr1_f(A, 0.0f);             // lane 0 -> 0
        row0v = fmaf(d0, Xm1, a0);
        row1v = A;
    };

    // ---- pipelined main loop: gather tile k+1 || scan tile k ----
    for (int k = 0; k < NT / TT; ++k) {
        if (wave == 0) {
            const float* Xt = &Xb[k & 1][0][0];
            const float* Yt = &Yb[k & 1][0][0];
            const int tb   = k * TT;
            const int nst  = (k == NT / TT - 1) ? TT - 1 : TT;   // 127 steps total
            #pragma unroll 4
            for (int tt = 0; tt < nst; ++tt) {
                const float2 cX = *(const float2*)&Xt[tt * XP + j0];
                const float2 cY = *(const float2*)&Yt[tt * XP + j0];
                step(cX.x, cX.y, cY.x, cY.y, tg[tb + tt + 1]);
            }
        } else if (k < NT / TT - 1) {
            const int tid7  = tid - 64;           // 0..447 ; 448 % 32 == 0
            const int tt    = tid7 & 31;
            const int tgt   = tg[(k + 1) * TT + tt];
            float* __restrict__ Xd = &Xb[(k + 1) & 1][tt][0];
            float* __restrict__ Yd = &Yb[(k + 1) & 1][tt][0];
            #pragma unroll 8
            for (int row = tid7 >> 5; row < 2 * NY; row += 448 / 32) {
                const int j = row & (NY - 1);
                const float v = (row < NY ? predB : IB)[(size_t)j * C_DIM + tgt];
                (row < NY ? Xd : Yd)[j] = v;
            }
        }
        __syncthreads();
    }

    if (wave == 0 && lane == 63) out[b] = row1v;
}

extern "C" void kernel_launch(void* const* d_in, const int* in_sizes, int n_in,
                              void* d_out, int out_size, void* d_ws, size_t ws_size,
                              hipStream_t stream) {
    const float* pred   = (const float*)d_in[0];
    const float* R      = (const float*)d_in[1];
    const float* I      = (const float*)d_in[2];
    const int*   target = (const int*)d_in[3];
    float* out = (float*)d_out;

    (void)d_ws; (void)ws_size; (void)in_sizes; (void)n_in; (void)out_size;

    eploss_fused<<<dim3(B_DIM), dim3(512), 0, stream>>>(pred, R, I, target, out);
}

// Round 4
// 558.026 us; speedup vs baseline: 1.1900x; 1.1900x over previous
//
#include <hip/hip_runtime.h>

#define B_DIM 1024
#define NT 128
#define NY 128
#define C_DIM 512
#define EOS 1
#define XP 130   // [t][j] LDS row stride (floats): write bank = (2*lane + j) % 32 -> 2-way (free)

// ---------------- DPP helpers (gfx9 lineage: row_shr / row_bcast / wave_shr) --------
template <int CTRL, int RM>
__device__ __forceinline__ float dpp_mov_f(float src, float oldv) {
    return __int_as_float(__builtin_amdgcn_update_dpp(
        __float_as_int(oldv), __float_as_int(src), CTRL, RM, 0xf, false));
}

__device__ __forceinline__ float wave_shr1_f(float src, float oldv) {
    return dpp_mov_f<0x138, 0xf>(src, oldv);   // wave_shr:1, lane 0 gets oldv
}

template <int CTRL, int RM>
__device__ __forceinline__ void scan_stage(float& A, float& D) {
    const float Ap = dpp_mov_f<CTRL, RM>(A, 0.0f);
    const float Dp = dpp_mov_f<CTRL, RM>(D, 1.0f);
    A = fmaf(Ap, D, A);
    D = D * Dp;
}

__device__ __forceinline__ void affine_scan64(float& A, float& D) {
    scan_stage<0x111, 0xf>(A, D);   // row_shr:1
    scan_stage<0x112, 0xf>(A, D);   // row_shr:2
    scan_stage<0x114, 0xf>(A, D);   // row_shr:4
    scan_stage<0x118, 0xf>(A, D);   // row_shr:8
    scan_stage<0x142, 0xa>(A, D);   // row_bcast:15 -> rows 1,3
    scan_stage<0x143, 0xc>(A, D);   // row_bcast:31 -> rows 2,3
}

__device__ __forceinline__ float mul_scan64(float P) {
    P *= dpp_mov_f<0x111, 0xf>(P, 1.0f);
    P *= dpp_mov_f<0x112, 0xf>(P, 1.0f);
    P *= dpp_mov_f<0x114, 0xf>(P, 1.0f);
    P *= dpp_mov_f<0x118, 0xf>(P, 1.0f);
    P *= dpp_mov_f<0x142, 0xa>(P, 1.0f);
    P *= dpp_mov_f<0x143, 0xc>(P, 1.0f);
    return P;
}

// ---------------- Fused kernel: whole-G-in-LDS gather + scan ----------------
// One block per b, 8 waves, 133 KB static LDS. Each (b,j) row of pred/I is read
// from global EXACTLY ONCE (FETCH stays at the 264 MB L3-residency floor, no
// tile refetch, no G round-trip). Wave w gathers 32 of the 256 rows with the
// round-0 pattern: lane <-> t, two scattered loads per row instruction (all 64
// addresses inside one 2 KB row -> L1/MSHR-merged), LDS write lands transposed
// into [t][j]. Wave 0 then runs the DPP scan out of LDS; writes = 4 KB total.
__global__ __launch_bounds__(512) void eploss_fused(
    const float* __restrict__ pred,
    const float* __restrict__ R,
    const float* __restrict__ I,
    const int*   __restrict__ target,
    float*       __restrict__ out)
{
    __shared__ float Xb[NT][XP];   // G_pred [t][j]
    __shared__ float Yb[NT][XP];   // G_I    [t][j]
    __shared__ int   tg[NT];

    const int b    = blockIdx.x;
    const int tid  = threadIdx.x;
    const int wave = tid >> 6;
    const int lane = tid & 63;

    if (tid < NT) tg[tid] = target[(size_t)b * NT + tid];
    __syncthreads();

    const int tA = tg[lane];        // t = lane
    const int tB = tg[64 + lane];   // t = 64 + lane

    // ---- gather: wave w owns rows w*32 .. w*32+31 of the 256 (pred|I) rows ----
    {
        const int r0 = wave * 32;
        const float* __restrict__ srcArr = (r0 >= NY) ? I : pred;
        float (* __restrict__ dst)[XP] = (r0 >= NY) ? Yb : Xb;
        const int jb = r0 & (NY - 1);
        const float* src = srcArr + ((size_t)b * NY + jb) * C_DIM;
        #pragma unroll 8
        for (int i = 0; i < 32; ++i) {
            const float vA = src[tA];
            const float vB = src[tB];
            const int j = jb + i;
            dst[lane][j]      = vA;   // G[t=lane][j]
            dst[64 + lane][j] = vB;   // G[t=64+lane][j]
            src += C_DIM;
        }
    }
    __syncthreads();
    if (wave != 0) return;

    // ---------------- scan (wave 0, register-resident state) ----------------
    const int j0 = 2 * lane;
    const int j1 = 2 * lane + 1;

    const float* Rb = R + (size_t)b * NY * 3;
    const float R0j0 = Rb[j0 * 3 + 0];
    const float R1j0 = Rb[j0 * 3 + 1];
    const float R2j0 = Rb[j0 * 3 + 2];
    const float R0j1 = Rb[j1 * 3 + 0];
    const float R1j1 = Rb[j1 * 3 + 1];
    const float R2j1 = Rb[j1 * 3 + 2];
    const float R2m1 = wave_shr1_f(R2j1, 1.0f);   // R2[j0-1] (lane 0 value unused)

    // row0 = cumprod([1, pD0[1..127]])
    const int tgt0 = tg[0];
    const float e0 = (lane == 0) ? 1.0f : ((tgt0 == EOS) ? 1.0f : R2j0);
    const float e1 = (tgt0 == EOS) ? 1.0f : R2j1;
    float P = mul_scan64(e0 * e1);
    const float Pm1 = wave_shr1_f(P, 1.0f);       // lane 0 -> 1.0
    float row0v = Pm1 * e0;
    float row1v = P;

    auto step = [&](float p0, float p1, float q0, float q1, int tgt_next) {
        const float pC0 = R0j0 * p0;
        const float pC1 = R0j1 * p1;
        const float pI0 = R1j0 * q0;
        const float pI1 = (lane == 63) ? q1 : R1j1 * q1;   // p_I[...,127] = I_T
        const float m1    = row1v * pC1;
        const float mprev = wave_shr1_f(m1, 0.0f);          // lane 0 -> 0
        const float a0 = fmaf(row0v, pI0, mprev);
        const float a1 = row0v * pC0 + row1v * pI1;
        const bool  eosn = (tgt_next == EOS);
        const float d0 = (lane == 0 || eosn) ? 1.0f : R2m1;
        const float d1 = eosn ? 1.0f : R2j0;
        float A = fmaf(d1, a0, a1);
        float D = d1 * d0;
        affine_scan64(A, D);
        const float Xm1 = wave_shr1_f(A, 0.0f);             // lane 0 -> 0
        row0v = fmaf(d0, Xm1, a0);
        row1v = A;
    };

    float2 pX = *(const float2*)&Xb[0][j0];
    float2 pY = *(const float2*)&Yb[0][j0];
    int tnext = tg[1];
    for (int t = 0; t < NT - 2; ++t) {
        const float2 nX = *(const float2*)&Xb[t + 1][j0];
        const float2 nY = *(const float2*)&Yb[t + 1][j0];
        const int tnn = tg[t + 2];
        step(pX.x, pX.y, pY.x, pY.y, tnext);
        pX = nX; pY = nY; tnext = tnn;
    }
    step(pX.x, pX.y, pY.x, pY.y, tnext);   // t = 126, uses tg[127]

    if (lane == 63) out[b] = row1v;
}

extern "C" void kernel_launch(void* const* d_in, const int* in_sizes, int n_in,
                              void* d_out, int out_size, void* d_ws, size_t ws_size,
                              hipStream_t stream) {
    const float* pred   = (const float*)d_in[0];
    const float* R      = (const float*)d_in[1];
    const float* I      = (const float*)d_in[2];
    const int*   target = (const int*)d_in[3];
    float* out = (float*)d_out;

    (void)d_ws; (void)ws_size; (void)in_sizes; (void)n_in; (void)out_size;

    eploss_fused<<<dim3(B_DIM), dim3(512), 0, stream>>>(pred, R, I, target, out);
}

// Round 5
// 521.067 us; speedup vs baseline: 1.2744x; 1.0709x over previous
//
#include <hip/hip_runtime.h>

#define B_DIM 1024
#define NT 128
#define NY 128
#define C_DIM 512
#define EOS 1
#define XP 130   // [t][j] LDS row stride (floats): 130%32=2 -> 2-way bank aliasing (free)

// ---------------- DPP helpers (gfx9 lineage: row_shr / row_bcast / wave_shr) --------
template <int CTRL, int RM>
__device__ __forceinline__ float dpp_mov_f(float src, float oldv) {
    return __int_as_float(__builtin_amdgcn_update_dpp(
        __float_as_int(oldv), __float_as_int(src), CTRL, RM, 0xf, false));
}

__device__ __forceinline__ float wave_shr1_f(float src, float oldv) {
    return dpp_mov_f<0x138, 0xf>(src, oldv);   // wave_shr:1, lane 0 gets oldv
}

template <int CTRL, int RM>
__device__ __forceinline__ void scan_stage(float& A, float& D) {
    const float Ap = dpp_mov_f<CTRL, RM>(A, 0.0f);
    const float Dp = dpp_mov_f<CTRL, RM>(D, 1.0f);
    A = fmaf(Ap, D, A);
    D = D * Dp;
}

__device__ __forceinline__ void affine_scan64(float& A, float& D) {
    scan_stage<0x111, 0xf>(A, D);   // row_shr:1
    scan_stage<0x112, 0xf>(A, D);   // row_shr:2
    scan_stage<0x114, 0xf>(A, D);   // row_shr:4
    scan_stage<0x118, 0xf>(A, D);   // row_shr:8
    scan_stage<0x142, 0xa>(A, D);   // row_bcast:15 -> rows 1,3
    scan_stage<0x143, 0xc>(A, D);   // row_bcast:31 -> rows 2,3
}

__device__ __forceinline__ float mul_scan64(float P) {
    P *= dpp_mov_f<0x111, 0xf>(P, 1.0f);
    P *= dpp_mov_f<0x112, 0xf>(P, 1.0f);
    P *= dpp_mov_f<0x114, 0xf>(P, 1.0f);
    P *= dpp_mov_f<0x118, 0xf>(P, 1.0f);
    P *= dpp_mov_f<0x142, 0xa>(P, 1.0f);
    P *= dpp_mov_f<0x143, 0xc>(P, 1.0f);
    return P;
}

// ---------------- Fused kernel: half-G LDS + register-held half ----------------
// One block per b, 8 waves, 67 KB static LDS -> 2 blocks/CU. Each (b,j) row is
// read from global exactly once (both loads issued in the gather loop); the
// t<64 half goes straight to LDS, the t>=64 half is held in 32 VGPRs per wave
// across scan-A, then dumped to the same LDS space for scan-B. Block B's gather
// overlaps block A's scan on the same CU -> memory pipe never drains.
__global__ __launch_bounds__(512, 4) void eploss_fused(
    const float* __restrict__ pred,
    const float* __restrict__ R,
    const float* __restrict__ I,
    const int*   __restrict__ target,
    float*       __restrict__ out)
{
    __shared__ float Xb[64][XP];   // G_pred half [t-in-half][j]
    __shared__ float Yb[64][XP];   // G_I    half
    __shared__ int   tg[NT];

    const int b    = blockIdx.x;
    const int tid  = threadIdx.x;
    const int wave = tid >> 6;
    const int lane = tid & 63;

    if (tid < NT) tg[tid] = target[(size_t)b * NT + tid];
    __syncthreads();

    const int tA = tg[lane];        // t = lane        (half A)
    const int tB = tg[64 + lane];   // t = 64 + lane   (half B)

    // ---- gather: wave w owns rows w*32 .. w*32+31 of the 256 (pred|I) rows ----
    float hold[32];                       // half-B values, t = 64+lane, rows jb..jb+31
    const int r0 = wave * 32;
    const int jb = r0 & (NY - 1);
    {
        const float* __restrict__ srcArr = (r0 >= NY) ? I : pred;
        float (* __restrict__ dstA)[XP] = (r0 >= NY) ? Yb : Xb;
        const float* src = srcArr + ((size_t)b * NY + jb) * C_DIM;
        #pragma unroll
        for (int i = 0; i < 32; ++i) {
            dstA[lane][jb + i] = src[tA];   // half A -> LDS (transposed)
            hold[i] = src[tB];              // half B -> registers
            src += C_DIM;
        }
    }

    // ---- scan state (wave 0 only, register-resident across both halves) ----
    const int j0 = 2 * lane;
    const int j1 = 2 * lane + 1;
    float R0j0, R1j0, R2j0, R0j1, R1j1, R2j1, R2m1, row0v, row1v;
    if (wave == 0) {
        const float* Rb = R + (size_t)b * NY * 3;
        R0j0 = Rb[j0 * 3 + 0];
        R1j0 = Rb[j0 * 3 + 1];
        R2j0 = Rb[j0 * 3 + 2];
        R0j1 = Rb[j1 * 3 + 0];
        R1j1 = Rb[j1 * 3 + 1];
        R2j1 = Rb[j1 * 3 + 2];
        R2m1 = wave_shr1_f(R2j1, 1.0f);   // R2[j0-1] (lane 0 value unused)

        // row0 = cumprod([1, pD0[1..127]])
        const int tgt0 = tg[0];
        const float e0 = (lane == 0) ? 1.0f : ((tgt0 == EOS) ? 1.0f : R2j0);
        const float e1 = (tgt0 == EOS) ? 1.0f : R2j1;
        float P = mul_scan64(e0 * e1);
        const float Pm1 = wave_shr1_f(P, 1.0f);   // lane 0 -> 1.0
        row0v = Pm1 * e0;
        row1v = P;
    }

    auto step = [&](float p0, float p1, float q0, float q1, int tgt_next) {
        const float pC0 = R0j0 * p0;
        const float pC1 = R0j1 * p1;
        const float pI0 = R1j0 * q0;
        const float pI1 = (lane == 63) ? q1 : R1j1 * q1;   // p_I[...,127] = I_T
        const float m1    = row1v * pC1;
        const float mprev = wave_shr1_f(m1, 0.0f);          // lane 0 -> 0
        const float a0 = fmaf(row0v, pI0, mprev);
        const float a1 = row0v * pC0 + row1v * pI1;
        const bool  eosn = (tgt_next == EOS);
        const float d0 = (lane == 0 || eosn) ? 1.0f : R2m1;
        const float d1 = eosn ? 1.0f : R2j0;
        float A = fmaf(d1, a0, a1);
        float D = d1 * d0;
        affine_scan64(A, D);
        const float Xm1 = wave_shr1_f(A, 0.0f);             // lane 0 -> 0
        row0v = fmaf(d0, Xm1, a0);
        row1v = A;
    };

    __syncthreads();   // half A staged

    // ---- scan A: steps t = 0..63 (consume G[0..63], tg[1..64]) ----
    if (wave == 0) {
        __builtin_amdgcn_s_setprio(1);
        float2 pX = *(const float2*)&Xb[0][j0];
        float2 pY = *(const float2*)&Yb[0][j0];
        int tnext = tg[1];
        for (int t = 0; t < 63; ++t) {
            const float2 nX = *(const float2*)&Xb[t + 1][j0];
            const float2 nY = *(const float2*)&Yb[t + 1][j0];
            const int tnn = tg[t + 2];          // max tg[64]
            step(pX.x, pX.y, pY.x, pY.y, tnext);
            pX = nX; pY = nY; tnext = tnn;
        }
        step(pX.x, pX.y, pY.x, pY.y, tnext);    // t = 63, uses tg[64]
        __builtin_amdgcn_s_setprio(0);
    }
    __syncthreads();   // scan A done; LDS reusable

    // ---- dump half B from registers into the same LDS space ----
    {
        float (* __restrict__ dstB)[XP] = (r0 >= NY) ? Yb : Xb;
        #pragma unroll
        for (int i = 0; i < 32; ++i) {
            dstB[lane][jb + i] = hold[i];       // G[t=64+lane][j=jb+i]
        }
    }
    __syncthreads();   // half B staged

    // ---- scan B: steps t = 64..126 (consume G[64..126], tg[65..127]) ----
    if (wave == 0) {
        __builtin_amdgcn_s_setprio(1);
        float2 pX = *(const float2*)&Xb[0][j0];
        float2 pY = *(const float2*)&Yb[0][j0];
        int tnext = tg[65];
        for (int tt = 0; tt < 62; ++tt) {
            const float2 nX = *(const float2*)&Xb[tt + 1][j0];
            const float2 nY = *(const float2*)&Yb[tt + 1][j0];
            const int tnn = tg[tt + 66];        // max tg[127]
            step(pX.x, pX.y, pY.x, pY.y, tnext);
            pX = nX; pY = nY; tnext = tnn;
        }
        step(pX.x, pX.y, pY.x, pY.y, tnext);    // t = 126, uses tg[127]
        __builtin_amdgcn_s_setprio(0);

        if (lane == 63) out[b] = row1v;
    }
}

extern "C" void kernel_launch(void* const* d_in, const int* in_sizes, int n_in,
                              void* d_out, int out_size, void* d_ws, size_t ws_size,
                              hipStream_t stream) {
    const float* pred   = (const float*)d_in[0];
    const float* R      = (const float*)d_in[1];
    const float* I      = (const float*)d_in[2];
    const int*   target = (const int*)d_in[3];
    float* out = (float*)d_out;

    (void)d_ws; (void)ws_size; (void)in_sizes; (void)n_in; (void)out_size;

    eploss_fused<<<dim3(B_DIM), dim3(512), 0, stream>>>(pred, R, I, target, out);
}